// Round 8
// baseline (251.760 us; speedup 1.0000x reference)
//
#include <hip/hip_runtime.h>
#include <hip/hip_bf16.h>
#include <stdint.h>

typedef __bf16 bf16x8 __attribute__((ext_vector_type(8)));
typedef float f32x4 __attribute__((ext_vector_type(4)));

#define MFMA16(a, b, c) __builtin_amdgcn_mfma_f32_16x16x32_bf16((a), (b), (c), 0, 0, 0)
#define SB() __builtin_amdgcn_sched_barrier(0)

// fp32 -> bf16 RNE
__device__ __forceinline__ ushort f2bf(float f) {
  union { float f; uint32_t u; } a; a.f = f;
  uint32_t u = a.u;
  return (ushort)((u + 0x7fffu + ((u >> 16) & 1u)) >> 16);
}

// global -> LDS direct DMA, 16B per lane. LDS dest must be wave-uniform.
__device__ __forceinline__ void glds16(const void* g, void* l) {
  __builtin_amdgcn_global_load_lds(
      (const __attribute__((address_space(1))) uint32_t*)g,
      (__attribute__((address_space(3))) uint32_t*)l, 16, 0, 0);
}

// ---------------------------------------------------------------- convert (all)
// [0,2048) x -> xb ; [2048,10240) y -> yb ; [10240,14336) weights -> w*b
__global__ __launch_bounds__(256) void cvt_all(
    const float* __restrict__ x, const float* __restrict__ y,
    const float* __restrict__ wq, const float* __restrict__ wk,
    const float* __restrict__ wv, const float* __restrict__ wp,
    ushort* __restrict__ xb, ushort* __restrict__ yb,
    ushort* __restrict__ oq, ushort* __restrict__ ok,
    ushort* __restrict__ ov, ushort* __restrict__ op) {
  const int bid = blockIdx.x;
  const float* in;
  ushort* out;
  int i;
  if (bid < 2048) { in = x; out = xb; i = bid * 1024 + threadIdx.x * 4; }
  else if (bid < 10240) { in = y; out = yb; i = (bid - 2048) * 1024 + threadIdx.x * 4; }
  else {
    const int wb = bid - 10240;
    const int sel = wb >> 10;
    in = (sel == 0) ? wq : (sel == 1) ? wk : (sel == 2) ? wv : wp;
    out = (sel == 0) ? oq : (sel == 1) ? ok : (sel == 2) ? ov : op;
    i = (wb & 1023) * 1024 + threadIdx.x * 4;
  }
  float4 v = *(const float4*)(in + i);
  ushort4 o;
  o.x = f2bf(v.x); o.y = f2bf(v.y); o.z = f2bf(v.z); o.w = f2bf(v.w);
  *(ushort4*)(out + i) = o;
}

// ---------------------------------------------------------------- fused QKV GEMM
// 1152 blocks, 128x128 tiles, K=1024, T3-min pipeline (dbuf + counted stage).
// mode 0 (v in [0,128)):    Q = xb * WqT, bf16 out * qscale     (M=2048)
// mode 1 (v in [128,640)):  K = yb * WkT, bf16 out              (M=8192)
// mode 2 (v in [640,1152)): V = yb * WvT -> vT (B,H,D,L) layout (M=8192)
// Single 32KB LDS pool; V-transpose epilogue aliases the dbuf (post-barrier).
__global__ __launch_bounds__(256) void qkv_fused(
    const ushort* __restrict__ xb, const ushort* __restrict__ yb,
    const ushort* __restrict__ wqb, const ushort* __restrict__ wkb,
    const ushort* __restrict__ wvb,
    ushort* __restrict__ qbf, ushort* __restrict__ kbf, ushort* __restrict__ vtb,
    float qscale) {
  constexpr int NN = 1024, K = 1024;
  __shared__ char ldsraw[32 * 1024];
  ushort* ldsA = (ushort*)ldsraw;                 // [2][128*32] 16KB
  ushort* ldsB = (ushort*)(ldsraw + 16 * 1024);   // [2][128*32] 16KB
  ushort* ldsT = (ushort*)ldsraw;                 // EPI1 alias [4][64*64] 32KB

  const int tid = threadIdx.x;
  const int w = tid >> 6, l = tid & 63;
  const int wm = w >> 1, wn = w & 1;

  // XCD-bijective swizzle (1152 = 8 * 144)
  const int bid = blockIdx.x;
  const int v = (bid & 7) * 144 + (bid >> 3);

  int mode, m0, n0;
  const ushort* A;
  const ushort* Bw;
  if (v < 128)      { mode = 0; const int vv = v;       n0 = (vv >> 4) * 128; m0 = (vv & 15) * 128; A = xb; Bw = wqb; }
  else if (v < 640) { mode = 1; const int vv = v - 128; n0 = (vv >> 6) * 128; m0 = (vv & 63) * 128; A = yb; Bw = wkb; }
  else              { mode = 2; const int vv = v - 640; n0 = (vv >> 6) * 128; m0 = (vv & 63) * 128; A = yb; Bw = wvb; }

  f32x4 acc[4][4] = {};

  const int srow = l >> 2;
  const int schunk = l & 3;

  auto stage = [&](int buf, int kt) {
#pragma unroll
    for (int r = 0; r < 2; ++r) {
      const int rb = r * 64 + w * 16;
      const int row = rb + srow;
      const int j = schunk ^ ((row >> 1) & 3);
      glds16(A + (size_t)(m0 + row) * K + kt + j * 8, (char*)ldsA + buf * 8192 + rb * 64);
      glds16(Bw + (size_t)(n0 + row) * K + kt + j * 8, (char*)ldsB + buf * 8192 + rb * 64);
    }
  };

  stage(0, 0);
  asm volatile("s_waitcnt vmcnt(0)" ::: "memory");
  SB(); __builtin_amdgcn_s_barrier(); SB();

  for (int t = 0; t < 32; ++t) {
    const int buf = t & 1;
    if (t + 1 < 32) stage(buf ^ 1, (t + 1) * 32);
    bf16x8 af[4], bfr[4];
#pragma unroll
    for (int a = 0; a < 4; ++a) {
      const int rt = wm * 64 + a * 16 + (l & 15);
      const int j = (l >> 4) ^ ((rt >> 1) & 3);
      af[a] = *(const bf16x8*)((const char*)ldsA + buf * 8192 + rt * 64 + j * 16);
    }
#pragma unroll
    for (int bx = 0; bx < 4; ++bx) {
      const int rt = wn * 64 + bx * 16 + (l & 15);
      const int j = (l >> 4) ^ ((rt >> 1) & 3);
      bfr[bx] = *(const bf16x8*)((const char*)ldsB + buf * 8192 + rt * 64 + j * 16);
    }
#pragma unroll
    for (int am = 0; am < 4; ++am)
#pragma unroll
      for (int bn = 0; bn < 4; ++bn)
        acc[am][bn] = MFMA16(af[am], bfr[bn], acc[am][bn]);
    if (t + 1 < 32) {
      asm volatile("s_waitcnt vmcnt(0)" ::: "memory");
      SB(); __builtin_amdgcn_s_barrier(); SB();
    }
  }

  if (mode == 0) {
#pragma unroll
    for (int am = 0; am < 4; ++am)
#pragma unroll
      for (int bn = 0; bn < 4; ++bn)
#pragma unroll
        for (int i = 0; i < 4; ++i) {
          const int row = m0 + wm * 64 + am * 16 + (l >> 4) * 4 + i;
          const int col = n0 + wn * 64 + bn * 16 + (l & 15);
          qbf[(size_t)row * NN + col] = f2bf(acc[am][bn][i] * qscale);
        }
  } else if (mode == 1) {
#pragma unroll
    for (int am = 0; am < 4; ++am)
#pragma unroll
      for (int bn = 0; bn < 4; ++bn)
#pragma unroll
        for (int i = 0; i < 4; ++i) {
          const int row = m0 + wm * 64 + am * 16 + (l >> 4) * 4 + i;
          const int col = n0 + wn * 64 + bn * 16 + (l & 15);
          kbf[(size_t)row * NN + col] = f2bf(acc[am][bn][i]);
        }
  } else {
    // V: transpose 64x64 wave tile in (aliased) LDS, coalesced stores along L.
    __syncthreads();   // all waves done with dbuf reads before aliasing
    ushort* tp = ldsT + w * 4096;
#pragma unroll
    for (int am = 0; am < 4; ++am)
#pragma unroll
      for (int bn = 0; bn < 4; ++bn)
#pragma unroll
        for (int i = 0; i < 4; ++i) {
          const int ml = am * 16 + (l >> 4) * 4 + i;
          const int cl = bn * 16 + (l & 15);
          tp[cl * 64 + ml] = f2bf(acc[am][bn][i]);
        }
    __syncthreads();
#pragma unroll
    for (int it = 0; it < 8; ++it) {
      const int cl = it * 8 + (l >> 3);
      const int mc = l & 7;
      bf16x8 vv = *(const bf16x8*)(tp + cl * 64 + mc * 8);
      const int gcol = n0 + wn * 64 + cl;   // 0..1023 -> (h,d)
      const int gm = m0 + wm * 64 + mc * 8; // 0..8191 -> (b,l_)
      const int b = gm >> 12;
      const int l_ = gm & 4095;
      const int h = gcol >> 6, d = gcol & 63;
      *(bf16x8*)(vtb + (((size_t)b * 16 + h) * 64 + d) * 4096 + l_) = vv;
    }
  }
}

// ---------------------------------------------------------------- out-proj GEMM
// out[m][n] = sum_k A[m][k] * Bw[n][k], 64x64 tiles, f32 out + bias.
__global__ __launch_bounds__(256) void gemm_out(
    const ushort* __restrict__ A, const ushort* __restrict__ Bw,
    float* __restrict__ Cout, const float* __restrict__ bias) {
  constexpr int NN = 1024, K = 1024;
  __shared__ ushort ldsA[2][64 * 32];
  __shared__ ushort ldsB[2][64 * 32];

  const int tid = threadIdx.x;
  const int w = tid >> 6, l = tid & 63;
  const int wm = w >> 1, wn = w & 1;
  const int m0 = blockIdx.x * 64, n0 = blockIdx.y * 64;

  f32x4 acc[2][2] = {};

  const int srow = l >> 2;
  const int schunk = l & 3;

  auto stage = [&](int buf, int kt) {
    const int rb = w * 16;
    const int row = rb + srow;
    const int j = schunk ^ ((row >> 1) & 3);
    glds16(A + (size_t)(m0 + row) * K + kt + j * 8, (char*)&ldsA[buf][0] + rb * 64);
    glds16(Bw + (size_t)(n0 + row) * K + kt + j * 8, (char*)&ldsB[buf][0] + rb * 64);
  };

  stage(0, 0);
  asm volatile("s_waitcnt vmcnt(0)" ::: "memory");
  SB(); __builtin_amdgcn_s_barrier(); SB();

  for (int t = 0; t < 32; ++t) {
    const int buf = t & 1;
    if (t + 1 < 32) stage(buf ^ 1, (t + 1) * 32);
    bf16x8 af[2], bfr[2];
#pragma unroll
    for (int a = 0; a < 2; ++a) {
      const int rt = wm * 32 + a * 16 + (l & 15);
      const int j = (l >> 4) ^ ((rt >> 1) & 3);
      af[a] = *(const bf16x8*)((const char*)&ldsA[buf][0] + rt * 64 + j * 16);
    }
#pragma unroll
    for (int bx = 0; bx < 2; ++bx) {
      const int rt = wn * 32 + bx * 16 + (l & 15);
      const int j = (l >> 4) ^ ((rt >> 1) & 3);
      bfr[bx] = *(const bf16x8*)((const char*)&ldsB[buf][0] + rt * 64 + j * 16);
    }
#pragma unroll
    for (int am = 0; am < 2; ++am)
#pragma unroll
      for (int bn = 0; bn < 2; ++bn)
        acc[am][bn] = MFMA16(af[am], bfr[bn], acc[am][bn]);
    if (t + 1 < 32) {
      asm volatile("s_waitcnt vmcnt(0)" ::: "memory");
      SB(); __builtin_amdgcn_s_barrier(); SB();
    }
  }

#pragma unroll
  for (int am = 0; am < 2; ++am)
#pragma unroll
    for (int bn = 0; bn < 2; ++bn)
#pragma unroll
      for (int i = 0; i < 4; ++i) {
        const int row = m0 + wm * 32 + am * 16 + (l >> 4) * 4 + i;
        const int col = n0 + wn * 32 + bn * 16 + (l & 15);
        Cout[(size_t)row * NN + col] = acc[am][bn][i] + bias[col];
      }
}

// ---------------------------------------------------------------- fused attention
// (unchanged from R7 — hybrid 2x2 wave split, lambda/sigma verified)
__global__ __launch_bounds__(256) void attn_fused(
    const ushort* __restrict__ qb, const ushort* __restrict__ kb,
    const ushort* __restrict__ vT, ushort* __restrict__ ao) {
  constexpr int H = 16, D = 64, L = 4096, N = 1024, KB = 128;
  __shared__ char ldsraw[2 * KB * 64 * 2 + 2 * 64 * KB * 2];  // 64KB: K dbuf + V dbuf
  __shared__ float ldsM[4][32];
  __shared__ float ldsL[4][32];
  ushort* ldsK0 = (ushort*)ldsraw;                      // [2][KB*64]
  ushort* ldsV0 = (ushort*)(ldsraw + 2 * KB * 64 * 2);  // [2][64*KB]
  float* ldsO = (float*)ldsraw;                         // merge alias [4][32][68]

  const int tid = threadIdx.x, w = tid >> 6, l = tid & 63;
  const int wq = w >> 1, wl = w & 1;
  const int wg = blockIdx.x;
  const int v = (wg & 7) * 64 + (wg >> 3);
  const int bh = v >> 4;
  const int n0 = (v & 15) * 64;
  const int b = bh >> 4, h = bh & 15;
  const int hq = l >> 4;
  const int m = l & 15;

  bf16x8 qf[2][2];
#pragma unroll
  for (int qa = 0; qa < 2; ++qa) {
    const ushort* qp = qb + (((size_t)b * N + n0 + 32 * wq + 16 * qa + m) * H + h) * D + hq * 8;
    qf[qa][0] = *(const bf16x8*)qp;
    qf[qa][1] = *(const bf16x8*)(qp + 32);
  }

  f32x4 oacc[2][4] = {};
  f32x4 lfr[2] = {};
  float m_run[2] = {-1e30f, -1e30f};

  bf16x8 vones;
#pragma unroll
  for (int j = 0; j < 8; ++j) vones[j] = (__bf16)1.0f;

  auto stage = [&](int buf, int l0) {
#pragma unroll
    for (int r = 0; r < 4; ++r) {
      const int rb = (w * 4 + r) * 8;
      const int row = rb + (l >> 3);
      const int sk = 4 * ((row >> 3) & 1) + (row & 3);
      const int j = (l & 7) ^ sk;
      glds16(kb + (((size_t)b * L + l0 + row) * H + h) * D + j * 8,
             (char*)(ldsK0 + buf * KB * 64) + rb * 128);
    }
#pragma unroll
    for (int r = 0; r < 4; ++r) {
      const int rb = (w * 4 + r) * 4;
      const int row = rb + (l >> 4);
      const int j = (l & 15) ^ (row & 15);
      glds16(vT + ((size_t)(b * H + h) * D + row) * L + l0 + j * 8,
             (char*)(ldsV0 + buf * 64 * KB) + rb * 256);
    }
  };

  stage(0, 0);

  const int sk = 4 * ((m >> 2) & 1) + (m & 3);
  const int rbase = 64 * wl + 8 * (m >> 2) + (m & 3);

  for (int t = 0; t < L / KB; ++t) {
    const int buf = t & 1;
    if (t < L / KB - 1) {
      stage(buf ^ 1, (t + 1) * KB);
      asm volatile("s_waitcnt vmcnt(8)" ::: "memory");
    } else {
      asm volatile("s_waitcnt vmcnt(0)" ::: "memory");
    }
    SB(); __builtin_amdgcn_s_barrier(); SB();

    const char* kbase = (const char*)(ldsK0 + buf * KB * 64);
    const char* vbase = (const char*)(ldsV0 + buf * 64 * KB);

    f32x4 sacc[2][2][2] = {};
    __builtin_amdgcn_s_setprio(1);
#pragma unroll
    for (int g = 0; g < 2; ++g)
#pragma unroll
      for (int la = 0; la < 2; ++la) {
        const int rt = rbase + 32 * g + 4 * la;
#pragma unroll
        for (int ks = 0; ks < 2; ++ks) {
          bf16x8 kf = *(const bf16x8*)(kbase + rt * 128 + (((ks * 4 + hq) ^ sk) << 4));
#pragma unroll
          for (int qa = 0; qa < 2; ++qa)
            sacc[g][la][qa] = MFMA16(kf, qf[qa][ks], sacc[g][la][qa]);
        }
      }
    __builtin_amdgcn_s_setprio(0);

    float mt[2];
#pragma unroll
    for (int qa = 0; qa < 2; ++qa) {
      float mq = sacc[0][0][qa][0];
#pragma unroll
      for (int g = 0; g < 2; ++g)
#pragma unroll
        for (int la = 0; la < 2; ++la)
#pragma unroll
          for (int i = 0; i < 4; ++i) mq = fmaxf(mq, sacc[g][la][qa][i]);
      mq = fmaxf(mq, __shfl_xor(mq, 16, 64));
      mq = fmaxf(mq, __shfl_xor(mq, 32, 64));
      mt[qa] = mq;
    }
    const bool ok = (mt[0] <= m_run[0] + 8.f) && (mt[1] <= m_run[1] + 8.f);
    if (!__all(ok)) {
#pragma unroll
      for (int qa = 0; qa < 2; ++qa) {
        const float mn = fmaxf(m_run[qa], mt[qa]);
        const float corr = __builtin_amdgcn_exp2f(m_run[qa] - mn);
        m_run[qa] = mn;
        f32x4 co;
#pragma unroll
        for (int i = 0; i < 4; ++i) co[i] = __shfl(corr, hq * 4 + i, 64);
#pragma unroll
        for (int c = 0; c < 4; ++c) oacc[qa][c] *= co;
        lfr[qa] *= co;
      }
    }
    bf16x8 pf[2][2];
#pragma unroll
    for (int g = 0; g < 2; ++g)
#pragma unroll
      for (int qa = 0; qa < 2; ++qa)
#pragma unroll
        for (int i = 0; i < 4; ++i) {
          pf[g][qa][i]     = (__bf16)__builtin_amdgcn_exp2f(sacc[g][0][qa][i] - m_run[qa]);
          pf[g][qa][4 + i] = (__bf16)__builtin_amdgcn_exp2f(sacc[g][1][qa][i] - m_run[qa]);
        }

    __builtin_amdgcn_s_setprio(1);
#pragma unroll
    for (int g = 0; g < 2; ++g) {
#pragma unroll
      for (int c = 0; c < 4; ++c) {
        const int rt = c * 16 + m;
        const int j = (8 * wl + 4 * g + hq) ^ (rt & 15);
        bf16x8 vf = *(const bf16x8*)(vbase + rt * 256 + (j << 4));
#pragma unroll
        for (int qa = 0; qa < 2; ++qa)
          oacc[qa][c] = MFMA16(pf[g][qa], vf, oacc[qa][c]);
      }
#pragma unroll
      for (int qa = 0; qa < 2; ++qa) lfr[qa] = MFMA16(pf[g][qa], vones, lfr[qa]);
    }
    __builtin_amdgcn_s_setprio(0);
    SB(); __builtin_amdgcn_s_barrier(); SB();
  }

#pragma unroll
  for (int qa = 0; qa < 2; ++qa)
#pragma unroll
    for (int c = 0; c < 4; ++c)
#pragma unroll
      for (int i = 0; i < 4; ++i)
        ldsO[w * 2176 + (16 * qa + 4 * hq + i) * 68 + 16 * c + m] = oacc[qa][c][i];
  if (hq == 0) {
#pragma unroll
    for (int qa = 0; qa < 2; ++qa) ldsM[w][16 * qa + m] = m_run[qa];
  }
  if (m == 0) {
#pragma unroll
    for (int qa = 0; qa < 2; ++qa)
#pragma unroll
      for (int i = 0; i < 4; ++i) ldsL[w][16 * qa + 4 * hq + i] = lfr[qa][i];
  }
  __syncthreads();

  const int q_local = 16 * (w & 1) + m;
  const int p0 = (w >> 1) * 2;
  const float Mx = fmaxf(ldsM[p0][q_local], ldsM[p0 + 1][q_local]);
  f32x4 av[4] = {};
  float Lt = 0.f;
#pragma unroll
  for (int p = 0; p < 2; ++p) {
    const int ws = p0 + p;
    const float sc = __builtin_amdgcn_exp2f(ldsM[ws][q_local] - Mx);
    Lt += ldsL[ws][q_local] * sc;
    const float* op = ldsO + ws * 2176 + q_local * 68 + hq * 16;
#pragma unroll
    for (int g = 0; g < 4; ++g) {
      f32x4 t4 = *(const f32x4*)(op + g * 4);
      av[g] += t4 * sc;
    }
  }
  const float inv = 1.0f / Lt;
  ushort* aop = ao + (((size_t)b * N + n0 + 16 * w + m) * H + h) * D + hq * 16;
#pragma unroll
  for (int g = 0; g < 4; ++g) {
    ushort4 o4;
    o4.x = f2bf(av[g][0] * inv); o4.y = f2bf(av[g][1] * inv);
    o4.z = f2bf(av[g][2] * inv); o4.w = f2bf(av[g][3] * inv);
    *(ushort4*)(aop + g * 4) = o4;
  }
}

// ---------------------------------------------------------------- launch
extern "C" void kernel_launch(void* const* d_in, const int* in_sizes, int n_in,
                              void* d_out, int out_size, void* d_ws, size_t ws_size,
                              hipStream_t stream) {
  const float* x  = (const float*)d_in[0];  // (2,1024,1024)
  const float* y  = (const float*)d_in[1];  // (2,4096,1024)
  const float* Wq = (const float*)d_in[2];
  const float* Wk = (const float*)d_in[3];
  const float* Wv = (const float*)d_in[4];
  const float* Wp = (const float*)d_in[5];
  const float* bp = (const float*)d_in[6];
  float* out = (float*)d_out;

  const size_t M1 = 1u << 20;
  ushort* wsb = (ushort*)d_ws;
  ushort* xb  = wsb;             // 2M elems
  ushort* yb  = wsb + 2 * M1;    // 8M
  ushort* wqb = wsb + 10 * M1;   // 1M
  ushort* wkb = wsb + 11 * M1;
  ushort* wvb = wsb + 12 * M1;
  ushort* wpb = wsb + 13 * M1;
  ushort* qbf = wsb + 14 * M1;   // 2M
  ushort* kbf = wsb + 16 * M1;   // 8M
  ushort* vtb = wsb + 24 * M1;   // 8M
  ushort* aob = wsb + 32 * M1;   // 2M  (total 34M elems = 68 MB)

  cvt_all<<<14336, 256, 0, stream>>>(x, y, Wq, Wk, Wv, Wp,
                                     xb, yb, wqb, wkb, wvb, wpb);

  const float qscale = 0.125f * 1.4426950408889634f;  // SCALE * log2(e)
  qkv_fused<<<1152, 256, 0, stream>>>(xb, yb, wqb, wkb, wvb, qbf, kbf, vtb, qscale);

  attn_fused<<<512, 256, 0, stream>>>(qbf, kbf, vtb, aob);

  gemm_out<<<dim3(32, 16), 256, 0, stream>>>(aob, wpb, out, bp);
}

// Round 10
// 243.952 us; speedup vs baseline: 1.0320x; 1.0320x over previous
//
#include <hip/hip_runtime.h>
#include <hip/hip_bf16.h>
#include <stdint.h>

typedef __bf16 bf16x8 __attribute__((ext_vector_type(8)));
typedef float f32x4 __attribute__((ext_vector_type(4)));

#define MFMA16(a, b, c) __builtin_amdgcn_mfma_f32_16x16x32_bf16((a), (b), (c), 0, 0, 0)
#define SB() __builtin_amdgcn_sched_barrier(0)

// fp32 -> bf16 RNE
__device__ __forceinline__ ushort f2bf(float f) {
  union { float f; uint32_t u; } a; a.f = f;
  uint32_t u = a.u;
  return (ushort)((u + 0x7fffu + ((u >> 16) & 1u)) >> 16);
}

// global -> LDS direct DMA, 16B per lane. LDS dest must be wave-uniform.
__device__ __forceinline__ void glds16(const void* g, void* l) {
  __builtin_amdgcn_global_load_lds(
      (const __attribute__((address_space(1))) uint32_t*)g,
      (__attribute__((address_space(3))) uint32_t*)l, 16, 0, 0);
}

// ---------------------------------------------------------------- convert (all)
// [0,2048) x -> xb ; [2048,10240) y -> yb ; [10240,14336) weights -> w*b
__global__ __launch_bounds__(256) void cvt_all(
    const float* __restrict__ x, const float* __restrict__ y,
    const float* __restrict__ wq, const float* __restrict__ wk,
    const float* __restrict__ wv, const float* __restrict__ wp,
    ushort* __restrict__ xb, ushort* __restrict__ yb,
    ushort* __restrict__ oq, ushort* __restrict__ ok,
    ushort* __restrict__ ov, ushort* __restrict__ op) {
  const int bid = blockIdx.x;
  const float* in;
  ushort* out;
  int i;
  if (bid < 2048) { in = x; out = xb; i = bid * 1024 + threadIdx.x * 4; }
  else if (bid < 10240) { in = y; out = yb; i = (bid - 2048) * 1024 + threadIdx.x * 4; }
  else {
    const int wb = bid - 10240;
    const int sel = wb >> 10;
    in = (sel == 0) ? wq : (sel == 1) ? wk : (sel == 2) ? wv : wp;
    out = (sel == 0) ? oq : (sel == 1) ? ok : (sel == 2) ? ov : op;
    i = (wb & 1023) * 1024 + threadIdx.x * 4;
  }
  float4 v = *(const float4*)(in + i);
  ushort4 o;
  o.x = f2bf(v.x); o.y = f2bf(v.y); o.z = f2bf(v.z); o.w = f2bf(v.w);
  *(ushort4*)(out + i) = o;
}

// ---------------------------------------------------------------- fused QKV GEMM
// 1152 blocks, 128x128 tiles, K=1024, T3-min pipeline (dbuf + counted stage).
// Block mapping (R9): n0-FAST, m0-slow, K/V interleaved per m-tile so blocks
// sharing an A-panel land contiguously on one XCD (L2-resident A + weights):
//   v <  128: Q  (m0 = (v>>3)*128,  n0 = (v&7)*128)         A=xb, W=Wq
//   v >= 128: vv = v-128; mi = vv>>4; r = vv&15;
//             m0 = mi*128; n0 = (r&7)*128; mode = r<8 ? K : V  (A=yb)
// Single 32KB LDS pool; V-transpose epilogue aliases the dbuf (post-barrier).
__global__ __launch_bounds__(256) void qkv_fused(
    const ushort* __restrict__ xb, const ushort* __restrict__ yb,
    const ushort* __restrict__ wqb, const ushort* __restrict__ wkb,
    const ushort* __restrict__ wvb,
    ushort* __restrict__ qbf, ushort* __restrict__ kbf, ushort* __restrict__ vtb,
    float qscale) {
  constexpr int NN = 1024, K = 1024;
  __shared__ char ldsraw[32 * 1024];
  ushort* ldsA = (ushort*)ldsraw;                 // [2][128*32] 16KB
  ushort* ldsB = (ushort*)(ldsraw + 16 * 1024);   // [2][128*32] 16KB
  ushort* ldsT = (ushort*)ldsraw;                 // EPI1 alias [4][64*64] 32KB

  const int tid = threadIdx.x;
  const int w = tid >> 6, l = tid & 63;
  const int wm = w >> 1, wn = w & 1;

  // XCD-bijective swizzle (1152 = 8 * 144)
  const int bid = blockIdx.x;
  const int v = (bid & 7) * 144 + (bid >> 3);

  int mode, m0, n0;
  const ushort* A;
  const ushort* Bw;
  if (v < 128) {
    mode = 0; m0 = (v >> 3) * 128; n0 = (v & 7) * 128; A = xb; Bw = wqb;
  } else {
    const int vv = v - 128;
    const int mi = vv >> 4, r = vv & 15;
    m0 = mi * 128; n0 = (r & 7) * 128; A = yb;
    if (r < 8) { mode = 1; Bw = wkb; }
    else       { mode = 2; Bw = wvb; }
  }

  f32x4 acc[4][4] = {};

  const int srow = l >> 2;
  const int schunk = l & 3;

  auto stage = [&](int buf, int kt) {
#pragma unroll
    for (int r = 0; r < 2; ++r) {
      const int rb = r * 64 + w * 16;
      const int row = rb + srow;
      const int j = schunk ^ ((row >> 1) & 3);
      glds16(A + (size_t)(m0 + row) * K + kt + j * 8, (char*)ldsA + buf * 8192 + rb * 64);
      glds16(Bw + (size_t)(n0 + row) * K + kt + j * 8, (char*)ldsB + buf * 8192 + rb * 64);
    }
  };

  stage(0, 0);
  asm volatile("s_waitcnt vmcnt(0)" ::: "memory");
  SB(); __builtin_amdgcn_s_barrier(); SB();

  for (int t = 0; t < 32; ++t) {
    const int buf = t & 1;
    if (t + 1 < 32) stage(buf ^ 1, (t + 1) * 32);
    bf16x8 af[4], bfr[4];
#pragma unroll
    for (int a = 0; a < 4; ++a) {
      const int rt = wm * 64 + a * 16 + (l & 15);
      const int j = (l >> 4) ^ ((rt >> 1) & 3);
      af[a] = *(const bf16x8*)((const char*)ldsA + buf * 8192 + rt * 64 + j * 16);
    }
#pragma unroll
    for (int bx = 0; bx < 4; ++bx) {
      const int rt = wn * 64 + bx * 16 + (l & 15);
      const int j = (l >> 4) ^ ((rt >> 1) & 3);
      bfr[bx] = *(const bf16x8*)((const char*)ldsB + buf * 8192 + rt * 64 + j * 16);
    }
#pragma unroll
    for (int am = 0; am < 4; ++am)
#pragma unroll
      for (int bn = 0; bn < 4; ++bn)
        acc[am][bn] = MFMA16(af[am], bfr[bn], acc[am][bn]);
    if (t + 1 < 32) {
      asm volatile("s_waitcnt vmcnt(0)" ::: "memory");
      SB(); __builtin_amdgcn_s_barrier(); SB();
    }
  }

  if (mode == 0) {
#pragma unroll
    for (int am = 0; am < 4; ++am)
#pragma unroll
      for (int bn = 0; bn < 4; ++bn)
#pragma unroll
        for (int i = 0; i < 4; ++i) {
          const int row = m0 + wm * 64 + am * 16 + (l >> 4) * 4 + i;
          const int col = n0 + wn * 64 + bn * 16 + (l & 15);
          qbf[(size_t)row * NN + col] = f2bf(acc[am][bn][i] * qscale);
        }
  } else if (mode == 1) {
#pragma unroll
    for (int am = 0; am < 4; ++am)
#pragma unroll
      for (int bn = 0; bn < 4; ++bn)
#pragma unroll
        for (int i = 0; i < 4; ++i) {
          const int row = m0 + wm * 64 + am * 16 + (l >> 4) * 4 + i;
          const int col = n0 + wn * 64 + bn * 16 + (l & 15);
          kbf[(size_t)row * NN + col] = f2bf(acc[am][bn][i]);
        }
  } else {
    // V: transpose 64x64 wave tile in (aliased) LDS, coalesced stores along L.
    __syncthreads();   // all waves done with dbuf reads before aliasing
    ushort* tp = ldsT + w * 4096;
#pragma unroll
    for (int am = 0; am < 4; ++am)
#pragma unroll
      for (int bn = 0; bn < 4; ++bn)
#pragma unroll
        for (int i = 0; i < 4; ++i) {
          const int ml = am * 16 + (l >> 4) * 4 + i;
          const int cl = bn * 16 + (l & 15);
          tp[cl * 64 + ml] = f2bf(acc[am][bn][i]);
        }
    __syncthreads();
#pragma unroll
    for (int it = 0; it < 8; ++it) {
      const int cl = it * 8 + (l >> 3);
      const int mc = l & 7;
      bf16x8 vv = *(const bf16x8*)(tp + cl * 64 + mc * 8);
      const int gcol = n0 + wn * 64 + cl;   // 0..1023 -> (h,d)
      const int gm = m0 + wm * 64 + mc * 8; // 0..8191 -> (b,l_)
      const int b = gm >> 12;
      const int l_ = gm & 4095;
      const int h = gcol >> 6, d = gcol & 63;
      *(bf16x8*)(vtb + (((size_t)b * 16 + h) * 64 + d) * 4096 + l_) = vv;
    }
  }
}

// ---------------------------------------------------------------- out-proj GEMM
// out[m][n] = sum_k A[m][k] * Bw[n][k], 64x64 tiles, f32 out + bias.
__global__ __launch_bounds__(256) void gemm_out(
    const ushort* __restrict__ A, const ushort* __restrict__ Bw,
    float* __restrict__ Cout, const float* __restrict__ bias) {
  constexpr int NN = 1024, K = 1024;
  __shared__ ushort ldsA[2][64 * 32];
  __shared__ ushort ldsB[2][64 * 32];

  const int tid = threadIdx.x;
  const int w = tid >> 6, l = tid & 63;
  const int wm = w >> 1, wn = w & 1;
  const int m0 = blockIdx.x * 64, n0 = blockIdx.y * 64;

  f32x4 acc[2][2] = {};

  const int srow = l >> 2;
  const int schunk = l & 3;

  auto stage = [&](int buf, int kt) {
    const int rb = w * 16;
    const int row = rb + srow;
    const int j = schunk ^ ((row >> 1) & 3);
    glds16(A + (size_t)(m0 + row) * K + kt + j * 8, (char*)&ldsA[buf][0] + rb * 64);
    glds16(Bw + (size_t)(n0 + row) * K + kt + j * 8, (char*)&ldsB[buf][0] + rb * 64);
  };

  stage(0, 0);
  asm volatile("s_waitcnt vmcnt(0)" ::: "memory");
  SB(); __builtin_amdgcn_s_barrier(); SB();

  for (int t = 0; t < 32; ++t) {
    const int buf = t & 1;
    if (t + 1 < 32) stage(buf ^ 1, (t + 1) * 32);
    bf16x8 af[2], bfr[2];
#pragma unroll
    for (int a = 0; a < 2; ++a) {
      const int rt = wm * 32 + a * 16 + (l & 15);
      const int j = (l >> 4) ^ ((rt >> 1) & 3);
      af[a] = *(const bf16x8*)((const char*)&ldsA[buf][0] + rt * 64 + j * 16);
    }
#pragma unroll
    for (int bx = 0; bx < 2; ++bx) {
      const int rt = wn * 32 + bx * 16 + (l & 15);
      const int j = (l >> 4) ^ ((rt >> 1) & 3);
      bfr[bx] = *(const bf16x8*)((const char*)&ldsB[buf][0] + rt * 64 + j * 16);
    }
#pragma unroll
    for (int am = 0; am < 2; ++am)
#pragma unroll
      for (int bn = 0; bn < 2; ++bn)
        acc[am][bn] = MFMA16(af[am], bfr[bn], acc[am][bn]);
    if (t + 1 < 32) {
      asm volatile("s_waitcnt vmcnt(0)" ::: "memory");
      SB(); __builtin_amdgcn_s_barrier(); SB();
    }
  }

#pragma unroll
  for (int am = 0; am < 2; ++am)
#pragma unroll
    for (int bn = 0; bn < 2; ++bn)
#pragma unroll
      for (int i = 0; i < 4; ++i) {
        const int row = m0 + wm * 32 + am * 16 + (l >> 4) * 4 + i;
        const int col = n0 + wn * 32 + bn * 16 + (l & 15);
        Cout[(size_t)row * NN + col] = acc[am][bn][i] + bias[col];
      }
}

// ---------------------------------------------------------------- fused attention
// (unchanged from R7 — hybrid 2x2 wave split, lambda/sigma verified)
__global__ __launch_bounds__(256) void attn_fused(
    const ushort* __restrict__ qb, const ushort* __restrict__ kb,
    const ushort* __restrict__ vT, ushort* __restrict__ ao) {
  constexpr int H = 16, D = 64, L = 4096, N = 1024, KB = 128;
  __shared__ char ldsraw[2 * KB * 64 * 2 + 2 * 64 * KB * 2];  // 64KB: K dbuf + V dbuf
  __shared__ float ldsM[4][32];
  __shared__ float ldsL[4][32];
  ushort* ldsK0 = (ushort*)ldsraw;                      // [2][KB*64]
  ushort* ldsV0 = (ushort*)(ldsraw + 2 * KB * 64 * 2);  // [2][64*KB]
  float* ldsO = (float*)ldsraw;                         // merge alias [4][32][68]

  const int tid = threadIdx.x, w = tid >> 6, l = tid & 63;
  const int wq = w >> 1, wl = w & 1;
  const int wg = blockIdx.x;
  const int v = (wg & 7) * 64 + (wg >> 3);
  const int bh = v >> 4;
  const int n0 = (v & 15) * 64;
  const int b = bh >> 4, h = bh & 15;
  const int hq = l >> 4;
  const int m = l & 15;

  bf16x8 qf[2][2];
#pragma unroll
  for (int qa = 0; qa < 2; ++qa) {
    const ushort* qp = qb + (((size_t)b * N + n0 + 32 * wq + 16 * qa + m) * H + h) * D + hq * 8;
    qf[qa][0] = *(const bf16x8*)qp;
    qf[qa][1] = *(const bf16x8*)(qp + 32);
  }

  f32x4 oacc[2][4] = {};
  f32x4 lfr[2] = {};
  float m_run[2] = {-1e30f, -1e30f};

  bf16x8 vones;
#pragma unroll
  for (int j = 0; j < 8; ++j) vones[j] = (__bf16)1.0f;

  auto stage = [&](int buf, int l0) {
#pragma unroll
    for (int r = 0; r < 4; ++r) {
      const int rb = (w * 4 + r) * 8;
      const int row = rb + (l >> 3);
      const int sk = 4 * ((row >> 3) & 1) + (row & 3);
      const int j = (l & 7) ^ sk;
      glds16(kb + (((size_t)b * L + l0 + row) * H + h) * D + j * 8,
             (char*)(ldsK0 + buf * KB * 64) + rb * 128);
    }
#pragma unroll
    for (int r = 0; r < 4; ++r) {
      const int rb = (w * 4 + r) * 4;
      const int row = rb + (l >> 4);
      const int j = (l & 15) ^ (row & 15);
      glds16(vT + ((size_t)(b * H + h) * D + row) * L + l0 + j * 8,
             (char*)(ldsV0 + buf * 64 * KB) + rb * 256);
    }
  };

  stage(0, 0);

  const int sk = 4 * ((m >> 2) & 1) + (m & 3);
  const int rbase = 64 * wl + 8 * (m >> 2) + (m & 3);

  for (int t = 0; t < L / KB; ++t) {
    const int buf = t & 1;
    if (t < L / KB - 1) {
      stage(buf ^ 1, (t + 1) * KB);
      asm volatile("s_waitcnt vmcnt(8)" ::: "memory");
    } else {
      asm volatile("s_waitcnt vmcnt(0)" ::: "memory");
    }
    SB(); __builtin_amdgcn_s_barrier(); SB();

    const char* kbase = (const char*)(ldsK0 + buf * KB * 64);
    const char* vbase = (const char*)(ldsV0 + buf * 64 * KB);

    f32x4 sacc[2][2][2] = {};
    __builtin_amdgcn_s_setprio(1);
#pragma unroll
    for (int g = 0; g < 2; ++g)
#pragma unroll
      for (int la = 0; la < 2; ++la) {
        const int rt = rbase + 32 * g + 4 * la;
#pragma unroll
        for (int ks = 0; ks < 2; ++ks) {
          bf16x8 kf = *(const bf16x8*)(kbase + rt * 128 + (((ks * 4 + hq) ^ sk) << 4));
#pragma unroll
          for (int qa = 0; qa < 2; ++qa)
            sacc[g][la][qa] = MFMA16(kf, qf[qa][ks], sacc[g][la][qa]);
        }
      }
    __builtin_amdgcn_s_setprio(0);

    float mt[2];
#pragma unroll
    for (int qa = 0; qa < 2; ++qa) {
      float mq = sacc[0][0][qa][0];
#pragma unroll
      for (int g = 0; g < 2; ++g)
#pragma unroll
        for (int la = 0; la < 2; ++la)
#pragma unroll
          for (int i = 0; i < 4; ++i) mq = fmaxf(mq, sacc[g][la][qa][i]);
      mq = fmaxf(mq, __shfl_xor(mq, 16, 64));
      mq = fmaxf(mq, __shfl_xor(mq, 32, 64));
      mt[qa] = mq;
    }
    const bool ok = (mt[0] <= m_run[0] + 8.f) && (mt[1] <= m_run[1] + 8.f);
    if (!__all(ok)) {
#pragma unroll
      for (int qa = 0; qa < 2; ++qa) {
        const float mn = fmaxf(m_run[qa], mt[qa]);
        const float corr = __builtin_amdgcn_exp2f(m_run[qa] - mn);
        m_run[qa] = mn;
        f32x4 co;
#pragma unroll
        for (int i = 0; i < 4; ++i) co[i] = __shfl(corr, hq * 4 + i, 64);
#pragma unroll
        for (int c = 0; c < 4; ++c) oacc[qa][c] *= co;
        lfr[qa] *= co;
      }
    }
    bf16x8 pf[2][2];
#pragma unroll
    for (int g = 0; g < 2; ++g)
#pragma unroll
      for (int qa = 0; qa < 2; ++qa)
#pragma unroll
        for (int i = 0; i < 4; ++i) {
          pf[g][qa][i]     = (__bf16)__builtin_amdgcn_exp2f(sacc[g][0][qa][i] - m_run[qa]);
          pf[g][qa][4 + i] = (__bf16)__builtin_amdgcn_exp2f(sacc[g][1][qa][i] - m_run[qa]);
        }

    __builtin_amdgcn_s_setprio(1);
#pragma unroll
    for (int g = 0; g < 2; ++g) {
#pragma unroll
      for (int c = 0; c < 4; ++c) {
        const int rt = c * 16 + m;
        const int j = (8 * wl + 4 * g + hq) ^ (rt & 15);
        bf16x8 vf = *(const bf16x8*)(vbase + rt * 256 + (j << 4));
#pragma unroll
        for (int qa = 0; qa < 2; ++qa)
          oacc[qa][c] = MFMA16(pf[g][qa], vf, oacc[qa][c]);
      }
#pragma unroll
      for (int qa = 0; qa < 2; ++qa) lfr[qa] = MFMA16(pf[g][qa], vones, lfr[qa]);
    }
    __builtin_amdgcn_s_setprio(0);
    SB(); __builtin_amdgcn_s_barrier(); SB();
  }

#pragma unroll
  for (int qa = 0; qa < 2; ++qa)
#pragma unroll
    for (int c = 0; c < 4; ++c)
#pragma unroll
      for (int i = 0; i < 4; ++i)
        ldsO[w * 2176 + (16 * qa + 4 * hq + i) * 68 + 16 * c + m] = oacc[qa][c][i];
  if (hq == 0) {
#pragma unroll
    for (int qa = 0; qa < 2; ++qa) ldsM[w][16 * qa + m] = m_run[qa];
  }
  if (m == 0) {
#pragma unroll
    for (int qa = 0; qa < 2; ++qa)
#pragma unroll
      for (int i = 0; i < 4; ++i) ldsL[w][16 * qa + 4 * hq + i] = lfr[qa][i];
  }
  __syncthreads();

  const int q_local = 16 * (w & 1) + m;
  const int p0 = (w >> 1) * 2;
  const float Mx = fmaxf(ldsM[p0][q_local], ldsM[p0 + 1][q_local]);
  f32x4 av[4] = {};
  float Lt = 0.f;
#pragma unroll
  for (int p = 0; p < 2; ++p) {
    const int ws = p0 + p;
    const float sc = __builtin_amdgcn_exp2f(ldsM[ws][q_local] - Mx);
    Lt += ldsL[ws][q_local] * sc;
    const float* op = ldsO + ws * 2176 + q_local * 68 + hq * 16;
#pragma unroll
    for (int g = 0; g < 4; ++g) {
      f32x4 t4 = *(const f32x4*)(op + g * 4);
      av[g] += t4 * sc;
    }
  }
  const float inv = 1.0f / Lt;
  ushort* aop = ao + (((size_t)b * N + n0 + 16 * w + m) * H + h) * D + hq * 16;
#pragma unroll
  for (int g = 0; g < 4; ++g) {
    ushort4 o4;
    o4.x = f2bf(av[g][0] * inv); o4.y = f2bf(av[g][1] * inv);
    o4.z = f2bf(av[g][2] * inv); o4.w = f2bf(av[g][3] * inv);
    *(ushort4*)(aop + g * 4) = o4;
  }
}

// ---------------------------------------------------------------- launch
extern "C" void kernel_launch(void* const* d_in, const int* in_sizes, int n_in,
                              void* d_out, int out_size, void* d_ws, size_t ws_size,
                              hipStream_t stream) {
  const float* x  = (const float*)d_in[0];  // (2,1024,1024)
  const float* y  = (const float*)d_in[1];  // (2,4096,1024)
  const float* Wq = (const float*)d_in[2];
  const float* Wk = (const float*)d_in[3];
  const float* Wv = (const float*)d_in[4];
  const float* Wp = (const float*)d_in[5];
  const float* bp = (const float*)d_in[6];
  float* out = (float*)d_out;

  const size_t M1 = 1u << 20;
  ushort* wsb = (ushort*)d_ws;
  ushort* xb  = wsb;             // 2M elems
  ushort* yb  = wsb + 2 * M1;    // 8M
  ushort* wqb = wsb + 10 * M1;   // 1M
  ushort* wkb = wsb + 11 * M1;
  ushort* wvb = wsb + 12 * M1;
  ushort* wpb = wsb + 13 * M1;
  ushort* qbf = wsb + 14 * M1;   // 2M
  ushort* kbf = wsb + 16 * M1;   // 8M
  ushort* vtb = wsb + 24 * M1;   // 8M
  ushort* aob = wsb + 32 * M1;   // 2M  (total 34M elems = 68 MB)

  cvt_all<<<14336, 256, 0, stream>>>(x, y, Wq, Wk, Wv, Wp,
                                     xb, yb, wqb, wkb, wvb, wpb);

  const float qscale = 0.125f * 1.4426950408889634f;  // SCALE * log2(e)
  qkv_fused<<<1152, 256, 0, stream>>>(xb, yb, wqb, wkb, wvb, qbf, kbf, vtb, qscale);

  attn_fused<<<512, 256, 0, stream>>>(qbf, kbf, vtb, aob);

  gemm_out<<<dim3(32, 16), 256, 0, stream>>>(aob, wpb, out, bp);
}